// Round 1
// baseline (100.102 us; speedup 1.0000x reference)
//
#include <hip/hip_runtime.h>
#include <math.h>

// Problem constants (from reference)
#define TB 4096   // batch
#define TN 39     // fields
#define TM 32     // embed dim
#define TD 32     // product layer dim
#define TH 400    // hidden width
#define BN_EPS 1e-3f

// ---------------------------------------------------------------------------
// Kernel A: fused embedding gather + l_z + l_p  -> x0 (B, 64)
//   l_z[b,d] = sum_{n,m} e[b,n,m] * lin_w[d,n,m]
//   l_p[b,d] = sum_n quad_w[d,n]^2 * (sum_m e[b,n,m]^2)
// One block = 4 batch rows; lin_w (160 KB, L2-resident) is re-read per block
// but each loaded float4 is reused across the 4 rows.
// ---------------------------------------------------------------------------
__global__ __launch_bounds__(256) void gather_product_kernel(
    const int* __restrict__ fidx,
    const float* __restrict__ emb,
    const float* __restrict__ lin_w,
    const float* __restrict__ quad_w,
    float* __restrict__ x0)
{
    constexpr int R = 4;
    __shared__ float e_s[R][TN * TM];   // 4 x 1248 floats = 20 KB
    __shared__ int   idx_s[R][TN];
    __shared__ float s_s[R][TN];

    const int t  = threadIdx.x;
    const int b0 = blockIdx.x * R;

    // Stage feature indices
    if (t < R * TN) {
        int r = t / TN, n = t - r * TN;
        idx_s[r][n] = fidx[(b0 + r) * TN + n];
    }
    __syncthreads();

    // Gather embeddings, vectorized float4 (8 float4 per 32-wide row)
    for (int r = 0; r < R; ++r) {
        for (int k4 = t; k4 < TN * TM / 4; k4 += 256) {
            int n = k4 >> 3;                       // row within field list
            int m = (k4 & 7) << 2;                 // element within row
            long long base = (long long)idx_s[r][n] * TM + m;
            *(float4*)&e_s[r][k4 * 4] = *(const float4*)&emb[base];
        }
    }
    __syncthreads();

    // l_z: thread t -> d = t>>3 (0..31), j = t&7 (8-way K split)
    {
        const int d = t >> 3, j = t & 7;
        float acc[R] = {0.f, 0.f, 0.f, 0.f};
        const float* lw_base = lin_w + d * (TN * TM);
        #pragma unroll 4
        for (int i = 0; i < TN; ++i) {
            float4 lw = *(const float4*)&lw_base[i * 32 + j * 4];
            #pragma unroll
            for (int r = 0; r < R; ++r) {
                float4 e4 = *(const float4*)&e_s[r][i * 32 + j * 4];
                acc[r] = fmaf(lw.x, e4.x, acc[r]);
                acc[r] = fmaf(lw.y, e4.y, acc[r]);
                acc[r] = fmaf(lw.z, e4.z, acc[r]);
                acc[r] = fmaf(lw.w, e4.w, acc[r]);
            }
        }
        // reduce across the 8-lane j group (lanes 8d..8d+7 contiguous in wave)
        #pragma unroll
        for (int off = 1; off < 8; off <<= 1)
            #pragma unroll
            for (int r = 0; r < R; ++r)
                acc[r] += __shfl_xor(acc[r], off);
        if (j == 0) {
            #pragma unroll
            for (int r = 0; r < R; ++r)
                x0[(b0 + r) * (2 * TD) + d] = acc[r];
        }
    }

    // s[n] = sum_m e^2 ; diagonal access pattern to dodge bank conflicts
    {
        int r = t >> 6, lane = t & 63;
        if (lane < TN) {
            float s = 0.f;
            #pragma unroll
            for (int mm = 0; mm < TM; ++mm) {
                float v = e_s[r][lane * TM + ((lane + mm) & 31)];
                s = fmaf(v, v, s);
            }
            s_s[r][lane] = s;
        }
    }
    __syncthreads();

    // l_p: threads 0..127 -> r = t>>5, d = t&31
    if (t < R * TD) {
        int r = t >> 5, d = t & 31;
        float acc = 0.f;
        for (int n = 0; n < TN; ++n) {
            float q = quad_w[d * TN + n];
            acc = fmaf(s_s[r][n], q * q, acc);
        }
        x0[(b0 + r) * (2 * TD) + TD + d] = acc;
    }
}

// ---------------------------------------------------------------------------
// Kernel B: fp32 GEMM layer with fused BN(inference) + ReLU
//   Y[b,h] = relu( (X@W)[b,h] * a[h] + c[h] )
//   a = g * rsqrt(rv+eps),  c = (bias - rm) * a + be
// Tile: BM=64 x BN=64, 256 threads, 4x4 microtile, BK=16.
// ---------------------------------------------------------------------------
template <int K>
__global__ __launch_bounds__(256) void mlp_layer_kernel(
    const float* __restrict__ X,     // B x K
    const float* __restrict__ W,     // K x TH
    const float* __restrict__ bias,
    const float* __restrict__ g,
    const float* __restrict__ be,
    const float* __restrict__ rm,
    const float* __restrict__ rv,
    float* __restrict__ Y)           // B x TH
{
    constexpr int BM = 64, BN = 64, BK = 16;
    __shared__ float xs[BK][BM + 4];   // stride 68 floats: 16B-aligned rows, 2-way max
    __shared__ float ws[BK][BN];

    const int t   = threadIdx.x;
    const int tx  = t & 15;            // output col group
    const int ty  = t >> 4;            // output row group
    const int bm  = blockIdx.x * BM;
    const int hn0 = blockIdx.y * BN;

    float acc[4][4] = {};

    for (int k0 = 0; k0 < K; k0 += BK) {
        // X tile (64 rows x 16 cols), transpose into xs[k][row]
        {
            int row = t >> 2, c4 = (t & 3) * 4;
            float4 xv = *(const float4*)&X[(bm + row) * K + k0 + c4];
            xs[c4 + 0][row] = xv.x;
            xs[c4 + 1][row] = xv.y;
            xs[c4 + 2][row] = xv.z;
            xs[c4 + 3][row] = xv.w;
        }
        // W tile (16 rows x 64 cols)
        {
            int row = t >> 4, c4 = (t & 15) * 4;
            int h = hn0 + c4;
            float4 wv = make_float4(0.f, 0.f, 0.f, 0.f);
            if (h + 3 < TH) wv = *(const float4*)&W[(k0 + row) * TH + h];
            *(float4*)&ws[row][c4] = wv;
        }
        __syncthreads();

        #pragma unroll
        for (int kk = 0; kk < BK; ++kk) {
            float4 xv = *(const float4*)&xs[kk][ty * 4];
            float4 wv = *(const float4*)&ws[kk][tx * 4];
            float xa[4] = {xv.x, xv.y, xv.z, xv.w};
            float wa[4] = {wv.x, wv.y, wv.z, wv.w};
            #pragma unroll
            for (int i = 0; i < 4; ++i)
                #pragma unroll
                for (int j = 0; j < 4; ++j)
                    acc[i][j] = fmaf(xa[i], wa[j], acc[i][j]);
        }
        __syncthreads();
    }

    // Epilogue: BN fold + ReLU, float4 stores
    const int hbase = hn0 + tx * 4;
    if (hbase + 3 < TH) {
        float a[4], c[4];
        #pragma unroll
        for (int j = 0; j < 4; ++j) {
            int h = hbase + j;
            float aj = g[h] * rsqrtf(rv[h] + BN_EPS);
            a[j] = aj;
            c[j] = (bias[h] - rm[h]) * aj + be[h];
        }
        #pragma unroll
        for (int i = 0; i < 4; ++i) {
            float4 o;
            o.x = fmaxf(fmaf(acc[i][0], a[0], c[0]), 0.f);
            o.y = fmaxf(fmaf(acc[i][1], a[1], c[1]), 0.f);
            o.z = fmaxf(fmaf(acc[i][2], a[2], c[2]), 0.f);
            o.w = fmaxf(fmaf(acc[i][3], a[3], c[3]), 0.f);
            *(float4*)&Y[(bm + ty * 4 + i) * TH + hbase] = o;
        }
    }
}

// ---------------------------------------------------------------------------
// Kernel C: out = sigmoid(X @ Wout + bout). One wave per batch row.
// ---------------------------------------------------------------------------
__global__ __launch_bounds__(256) void out_kernel(
    const float* __restrict__ X,      // B x TH
    const float* __restrict__ Wout,   // TH
    const float* __restrict__ bout,   // 1
    float* __restrict__ out)          // B
{
    const int wave = threadIdx.x >> 6;
    const int lane = threadIdx.x & 63;
    const int row  = blockIdx.x * 4 + wave;

    float s = 0.f;
    for (int k = lane; k < TH; k += 64)
        s = fmaf(X[row * TH + k], Wout[k], s);
    #pragma unroll
    for (int off = 32; off; off >>= 1)
        s += __shfl_xor(s, off);
    if (lane == 0)
        out[row] = 1.f / (1.f + expf(-(s + bout[0])));
}

// ---------------------------------------------------------------------------
extern "C" void kernel_launch(void* const* d_in, const int* in_sizes, int n_in,
                              void* d_out, int out_size, void* d_ws, size_t ws_size,
                              hipStream_t stream) {
    const int*   fidx   = (const int*)  d_in[0];
    // d_in[1] = feature_value: unused by the reference
    const float* emb    = (const float*)d_in[2];
    const float* lin_w  = (const float*)d_in[3];
    const float* quad_w = (const float*)d_in[4];

    const float* W0  = (const float*)d_in[5];
    const float* b0  = (const float*)d_in[6];
    const float* g0  = (const float*)d_in[7];
    const float* be0 = (const float*)d_in[8];
    const float* rm0 = (const float*)d_in[9];
    const float* rv0 = (const float*)d_in[10];

    const float* W1  = (const float*)d_in[11];
    const float* b1  = (const float*)d_in[12];
    const float* g1  = (const float*)d_in[13];
    const float* be1 = (const float*)d_in[14];
    const float* rm1 = (const float*)d_in[15];
    const float* rv1 = (const float*)d_in[16];

    const float* W2  = (const float*)d_in[17];
    const float* b2  = (const float*)d_in[18];
    const float* g2  = (const float*)d_in[19];
    const float* be2 = (const float*)d_in[20];
    const float* rm2 = (const float*)d_in[21];
    const float* rv2 = (const float*)d_in[22];

    const float* Wout = (const float*)d_in[23];
    const float* bout = (const float*)d_in[24];

    float* ws = (float*)d_ws;
    float* x0 = ws;                              // 4096 * 64
    float* x1 = x0 + (size_t)TB * 2 * TD;        // 4096 * 400
    float* x2 = x1 + (size_t)TB * TH;            // 4096 * 400
    float* x3 = x1;                              // reuse x1 (dead after layer 2)

    float* out = (float*)d_out;

    gather_product_kernel<<<TB / 4, 256, 0, stream>>>(fidx, emb, lin_w, quad_w, x0);

    dim3 gemm_grid(TB / 64, (TH + 63) / 64);
    mlp_layer_kernel<2 * TD><<<gemm_grid, 256, 0, stream>>>(x0, W0, b0, g0, be0, rm0, rv0, x1);
    mlp_layer_kernel<TH>    <<<gemm_grid, 256, 0, stream>>>(x1, W1, b1, g1, be1, rm1, rv1, x2);
    mlp_layer_kernel<TH>    <<<gemm_grid, 256, 0, stream>>>(x2, W2, b2, g2, be2, rm2, rv2, x3);

    out_kernel<<<TB / 4, 256, 0, stream>>>(x3, Wout, bout, out);
}

// Round 2
// 60.790 us; speedup vs baseline: 1.6467x; 1.6467x over previous
//
#include <hip/hip_runtime.h>
#include <hip/hip_bf16.h>
#include <math.h>

#define TB 4096   // batch
#define TN 39     // fields
#define TM 32     // embed dim
#define TD 32     // product layer dim
#define TH 400    // hidden width
#define BN_EPS 1e-3f

#define KT0 2     // layer-0 K=64  -> 2 chunks of K32
#define KTH 13    // layers 1/2 K=400 padded to 416 -> 13 chunks of K32

typedef __attribute__((ext_vector_type(8))) short bf16x8;
typedef __attribute__((ext_vector_type(4))) float f32x4;

// ---- fp32 -> bf16 hi/lo split (hi = truncation, lo = RN of remainder; exact sum of products
//      up to the dropped lo*lo term ~2^-16 relative) ----
__device__ __forceinline__ ushort bf16_rn(float x) {
    __hip_bfloat16 h = __float2bfloat16(x);
    union { __hip_bfloat16 b; ushort u; } c; c.b = h; return c.u;
}
__device__ __forceinline__ void split2(float x, ushort& hi, ushort& lo) {
    unsigned xb = __float_as_uint(x);
    unsigned hb = xb & 0xFFFF0000u;
    hi = (ushort)(hb >> 16);
    lo = bf16_rn(x - __uint_as_float(hb));   // exact remainder, then RN to bf16
}

// MFMA 16x16x32 bf16 fragment layout (A: row = l&15; B: col = l&15;
// k = 16*(j>>2) + 4*(l>>4) + (j&3), j = element 0..7). Panels are stored as
// [tile16][kt32][lane 64][j 8] ushorts; one (tile,kt) chunk = 512 ushorts = 1 KB.
__device__ __forceinline__ size_t panel_idx(int p, int k, int KT) {
    int lane_ = (p & 15) + 16 * ((k >> 2) & 3);
    int j_    = (k & 3) + 4 * ((k >> 4) & 1);
    return (((size_t)((p >> 4) * KT + (k >> 5)) * 64) + lane_) * 8 + j_;
}

// ---------------------------------------------------------------------------
// Fused front kernel.
//  blocks [0, 1024): embedding gather + l_z + l_p -> A0 panels (bf16 hi/lo)
//  blocks [1024, 1416): prepack W0/W1/W2 -> B panels (bf16 hi/lo, zero-padded)
// ---------------------------------------------------------------------------
__global__ __launch_bounds__(256) void fused_front_kernel(
    const int*   __restrict__ fidx,
    const float* __restrict__ emb,
    const float* __restrict__ lin_w,
    const float* __restrict__ quad_w,
    const float* __restrict__ W0,
    const float* __restrict__ W1,
    const float* __restrict__ W2,
    ushort* __restrict__ A0h, ushort* __restrict__ A0l,
    ushort* __restrict__ B0h, ushort* __restrict__ B0l,
    ushort* __restrict__ B1h, ushort* __restrict__ B1l,
    ushort* __restrict__ B2h, ushort* __restrict__ B2l)
{
    if (blockIdx.x >= TB / 4) {
        // ---------------- prepack path ----------------
        int tid = (blockIdx.x - TB / 4) * 256 + threadIdx.x;
        const float* W; ushort *Ph, *Pl; int k, n4, K, KT;
        if (tid < 64 * 112) {
            W = W0; Ph = B0h; Pl = B0l; k = tid / 112; n4 = tid % 112; K = 64; KT = KT0;
        } else if (tid < 64 * 112 + 416 * 112) {
            int u = tid - 64 * 112;
            W = W1; Ph = B1h; Pl = B1l; k = u / 112; n4 = u % 112; K = TH; KT = KTH;
        } else if (tid < 64 * 112 + 2 * 416 * 112) {
            int u = tid - 64 * 112 - 416 * 112;
            W = W2; Ph = B2h; Pl = B2l; k = u / 112; n4 = u % 112; K = TH; KT = KTH;
        } else {
            return;
        }
        int n0 = n4 * 4;
        float4 w = make_float4(0.f, 0.f, 0.f, 0.f);
        if (k < K && n0 < TH)                      // n0 multiple of 4; 400%4==0
            w = *(const float4*)&W[(size_t)k * TH + n0];
        float vals[4] = {w.x, w.y, w.z, w.w};
        #pragma unroll
        for (int i = 0; i < 4; ++i) {
            ushort hi, lo; split2(vals[i], hi, lo);
            size_t idx = panel_idx(n0 + i, k, KT);
            Ph[idx] = hi; Pl[idx] = lo;
        }
        return;
    }

    // ---------------- gather + product path ----------------
    constexpr int R = 4;
    __shared__ float e_s[R][TN * TM];
    __shared__ int   idx_s[R][TN];
    __shared__ float s_s[R][TN];

    const int t  = threadIdx.x;
    const int b0 = blockIdx.x * R;

    if (t < R * TN) {
        int r = t / TN, n = t - r * TN;
        idx_s[r][n] = fidx[(b0 + r) * TN + n];
    }
    __syncthreads();

    for (int r = 0; r < R; ++r) {
        for (int k4 = t; k4 < TN * TM / 4; k4 += 256) {
            int n = k4 >> 3;
            long long base = (long long)idx_s[r][n] * TM + ((k4 & 7) << 2);
            *(float4*)&e_s[r][k4 * 4] = *(const float4*)&emb[base];
        }
    }
    __syncthreads();

    // l_z: thread t -> d = t>>3, j = t&7 (8-way K split within wave)
    {
        const int d = t >> 3, j = t & 7;
        float acc[R] = {0.f, 0.f, 0.f, 0.f};
        const float* lw_base = lin_w + d * (TN * TM);
        #pragma unroll 4
        for (int i = 0; i < TN; ++i) {
            float4 lw = *(const float4*)&lw_base[i * 32 + j * 4];
            #pragma unroll
            for (int r = 0; r < R; ++r) {
                float4 e4 = *(const float4*)&e_s[r][i * 32 + j * 4];
                acc[r] = fmaf(lw.x, e4.x, acc[r]);
                acc[r] = fmaf(lw.y, e4.y, acc[r]);
                acc[r] = fmaf(lw.z, e4.z, acc[r]);
                acc[r] = fmaf(lw.w, e4.w, acc[r]);
            }
        }
        #pragma unroll
        for (int off = 1; off < 8; off <<= 1)
            #pragma unroll
            for (int r = 0; r < R; ++r)
                acc[r] += __shfl_xor(acc[r], off);
        if (j == 0) {
            #pragma unroll
            for (int r = 0; r < R; ++r) {
                ushort hi, lo; split2(acc[r], hi, lo);
                size_t idx = panel_idx(b0 + r, d, KT0);
                A0h[idx] = hi; A0l[idx] = lo;
            }
        }
    }

    // s[n] = sum_m e^2
    {
        int r = t >> 6, lane = t & 63;
        if (lane < TN) {
            float s = 0.f;
            #pragma unroll
            for (int mm = 0; mm < TM; ++mm) {
                float v = e_s[r][lane * TM + ((lane + mm) & 31)];
                s = fmaf(v, v, s);
            }
            s_s[r][lane] = s;
        }
    }
    __syncthreads();

    // l_p
    if (t < R * TD) {
        int r = t >> 5, d = t & 31;
        float accv = 0.f;
        for (int n = 0; n < TN; ++n) {
            float q = quad_w[d * TN + n];
            accv = fmaf(s_s[r][n], q * q, accv);
        }
        ushort hi, lo; split2(accv, hi, lo);
        size_t idx = panel_idx(b0 + r, TD + d, KT0);
        A0h[idx] = hi; A0l[idx] = lo;
    }
}

// ---------------------------------------------------------------------------
// Split-bf16 MFMA GEMM layer. One wave (64 thr) computes a 64x64 output tile
// as 4x4 fragments of 16x16. Operands are pre-packed fragment panels loaded
// straight from global (L2-resident); no LDS in the hot loop.
// Epilogue: fused BN+ReLU; PANEL_OUT repacks the result into the next layer's
// A-panels via an LDS transpose; otherwise writes fp32 Y.
// ---------------------------------------------------------------------------
template <int KT, bool PANEL_OUT>
__global__ __launch_bounds__(64) void mfma_layer_kernel(
    const ushort* __restrict__ Ah, const ushort* __restrict__ Al,
    const ushort* __restrict__ Bh, const ushort* __restrict__ Bl,
    const float* __restrict__ bias, const float* __restrict__ g,
    const float* __restrict__ be,   const float* __restrict__ rm,
    const float* __restrict__ rv,
    ushort* __restrict__ Nh, ushort* __restrict__ Nl,
    float* __restrict__ Yout)
{
    const int lane = threadIdx.x;
    const int bm = blockIdx.x & 63;   // 64 M-blocks of 64 rows
    const int bn = blockIdx.x >> 6;   // 7 N-blocks of 64 cols (448 padded)

    f32x4 acc[4][4];
    #pragma unroll
    for (int i = 0; i < 4; ++i)
        #pragma unroll
        for (int jx = 0; jx < 4; ++jx)
            acc[i][jx] = (f32x4){0.f, 0.f, 0.f, 0.f};

    const ushort* pAh = Ah + ((size_t)bm * 4 * KT) * 512 + lane * 8;
    const ushort* pAl = Al + ((size_t)bm * 4 * KT) * 512 + lane * 8;
    const ushort* pBh = Bh + ((size_t)bn * 4 * KT) * 512 + lane * 8;
    const ushort* pBl = Bl + ((size_t)bn * 4 * KT) * 512 + lane * 8;

    #pragma unroll 2
    for (int kt = 0; kt < KT; ++kt) {
        bf16x8 ah[4], al[4], bh[4], bl[4];
        #pragma unroll
        for (int m = 0; m < 4; ++m) {
            ah[m] = *(const bf16x8*)(pAh + (size_t)(m * KT + kt) * 512);
            al[m] = *(const bf16x8*)(pAl + (size_t)(m * KT + kt) * 512);
        }
        #pragma unroll
        for (int n = 0; n < 4; ++n) {
            bh[n] = *(const bf16x8*)(pBh + (size_t)(n * KT + kt) * 512);
            bl[n] = *(const bf16x8*)(pBl + (size_t)(n * KT + kt) * 512);
        }
        #pragma unroll
        for (int m = 0; m < 4; ++m)
            #pragma unroll
            for (int n = 0; n < 4; ++n) {
                acc[m][n] = __builtin_amdgcn_mfma_f32_16x16x32_bf16(ah[m], bh[n], acc[m][n], 0, 0, 0);
                acc[m][n] = __builtin_amdgcn_mfma_f32_16x16x32_bf16(ah[m], bl[n], acc[m][n], 0, 0, 0);
                acc[m][n] = __builtin_amdgcn_mfma_f32_16x16x32_bf16(al[m], bh[n], acc[m][n], 0, 0, 0);
            }
    }

    // C/D layout: col = lane&15, row = (lane>>4)*4 + reg
    const int col = lane & 15;
    const int rq  = (lane >> 4) << 2;

    if constexpr (PANEL_OUT) {
        __shared__ float ysm[64][68];   // padded stride: conflict-free
        #pragma unroll
        for (int nt = 0; nt < 4; ++nt) {
            int h = bn * 64 + nt * 16 + col;
            float aj = 0.f, cj = 0.f;
            if (h < TH) {
                aj = g[h] * rsqrtf(rv[h] + BN_EPS);
                cj = (bias[h] - rm[h]) * aj + be[h];
            }
            #pragma unroll
            for (int mt = 0; mt < 4; ++mt) {
                f32x4 v = acc[mt][nt];
                #pragma unroll
                for (int r = 0; r < 4; ++r)
                    ysm[mt * 16 + rq + r][nt * 16 + col] = fmaxf(v[r] * aj + cj, 0.f);
            }
        }
        __syncthreads();
        const int kq = (lane >> 4) << 2;
        #pragma unroll
        for (int mtl = 0; mtl < 4; ++mtl) {
            #pragma unroll
            for (int ck = 0; ck < 2; ++ck) {
                int kt32 = bn * 2 + ck;
                if (kt32 >= KTH) continue;          // h >= 416: outside panel
                int row_l = mtl * 16 + (lane & 15);
                int kb = ck * 32 + kq;
                float4 v0 = *(const float4*)&ysm[row_l][kb];
                float4 v1 = *(const float4*)&ysm[row_l][kb + 16];
                ushort h_[8], l_[8];
                split2(v0.x, h_[0], l_[0]); split2(v0.y, h_[1], l_[1]);
                split2(v0.z, h_[2], l_[2]); split2(v0.w, h_[3], l_[3]);
                split2(v1.x, h_[4], l_[4]); split2(v1.y, h_[5], l_[5]);
                split2(v1.z, h_[6], l_[6]); split2(v1.w, h_[7], l_[7]);
                uint4 H, L;
                H.x = (uint)h_[0] | ((uint)h_[1] << 16);
                H.y = (uint)h_[2] | ((uint)h_[3] << 16);
                H.z = (uint)h_[4] | ((uint)h_[5] << 16);
                H.w = (uint)h_[6] | ((uint)h_[7] << 16);
                L.x = (uint)l_[0] | ((uint)l_[1] << 16);
                L.y = (uint)l_[2] | ((uint)l_[3] << 16);
                L.z = (uint)l_[4] | ((uint)l_[5] << 16);
                L.w = (uint)l_[6] | ((uint)l_[7] << 16);
                size_t base = (((size_t)(bm * 4 + mtl) * KTH + kt32) * 64 + lane) * 8;
                *(uint4*)(Nh + base) = H;
                *(uint4*)(Nl + base) = L;
            }
        }
    } else {
        #pragma unroll
        for (int nt = 0; nt < 4; ++nt) {
            int h = bn * 64 + nt * 16 + col;
            if (h < TH) {
                float aj = g[h] * rsqrtf(rv[h] + BN_EPS);
                float cj = (bias[h] - rm[h]) * aj + be[h];
                #pragma unroll
                for (int mt = 0; mt < 4; ++mt) {
                    f32x4 v = acc[mt][nt];
                    #pragma unroll
                    for (int r = 0; r < 4; ++r)
                        Yout[(size_t)(bm * 64 + mt * 16 + rq + r) * TH + h] =
                            fmaxf(v[r] * aj + cj, 0.f);
                }
            }
        }
    }
}

// ---------------------------------------------------------------------------
// out = sigmoid(X @ Wout + bout). One wave per batch row.
// ---------------------------------------------------------------------------
__global__ __launch_bounds__(256) void out_kernel(
    const float* __restrict__ X,      // B x TH
    const float* __restrict__ Wout,   // TH
    const float* __restrict__ bout,   // 1
    float* __restrict__ out)          // B
{
    const int wave = threadIdx.x >> 6;
    const int lane = threadIdx.x & 63;
    const int row  = blockIdx.x * 4 + wave;

    float s = 0.f;
    for (int k = lane; k < TH; k += 64)
        s = fmaf(X[row * TH + k], Wout[k], s);
    #pragma unroll
    for (int off = 32; off; off >>= 1)
        s += __shfl_xor(s, off);
    if (lane == 0)
        out[row] = 1.f / (1.f + expf(-(s + bout[0])));
}

// ---------------------------------------------------------------------------
extern "C" void kernel_launch(void* const* d_in, const int* in_sizes, int n_in,
                              void* d_out, int out_size, void* d_ws, size_t ws_size,
                              hipStream_t stream) {
    const int*   fidx   = (const int*)  d_in[0];
    const float* emb    = (const float*)d_in[2];
    const float* lin_w  = (const float*)d_in[3];
    const float* quad_w = (const float*)d_in[4];

    const float* W0  = (const float*)d_in[5];
    const float* b0  = (const float*)d_in[6];
    const float* g0  = (const float*)d_in[7];
    const float* be0 = (const float*)d_in[8];
    const float* rm0 = (const float*)d_in[9];
    const float* rv0 = (const float*)d_in[10];

    const float* W1  = (const float*)d_in[11];
    const float* b1  = (const float*)d_in[12];
    const float* g1  = (const float*)d_in[13];
    const float* be1 = (const float*)d_in[14];
    const float* rm1 = (const float*)d_in[15];
    const float* rv1 = (const float*)d_in[16];

    const float* W2  = (const float*)d_in[17];
    const float* b2  = (const float*)d_in[18];
    const float* g2  = (const float*)d_in[19];
    const float* be2 = (const float*)d_in[20];
    const float* rm2 = (const float*)d_in[21];
    const float* rv2 = (const float*)d_in[22];

    const float* Wout = (const float*)d_in[23];
    const float* bout = (const float*)d_in[24];

    // Workspace carve-up (all chunk-multiples -> 16B aligned)
    const size_t SZ_A0 = (size_t)256 * KT0 * 512;   // A0 panels: 256 mt x 2 kt
    const size_t SZ_A  = (size_t)256 * KTH * 512;   // A1/A2 panels: 256 mt x 13 kt
    const size_t SZ_B0 = (size_t)28  * KT0 * 512;   // B0 panels: 28 nt x 2 kt
    const size_t SZ_B  = (size_t)28  * KTH * 512;   // B1/B2 panels: 28 nt x 13 kt

    ushort* p = (ushort*)d_ws;
    ushort *A0h = p; p += SZ_A0; ushort *A0l = p; p += SZ_A0;
    ushort *A1h = p; p += SZ_A;  ushort *A1l = p; p += SZ_A;
    ushort *A2h = p; p += SZ_A;  ushort *A2l = p; p += SZ_A;
    ushort *B0h = p; p += SZ_B0; ushort *B0l = p; p += SZ_B0;
    ushort *B1h = p; p += SZ_B;  ushort *B1l = p; p += SZ_B;
    ushort *B2h = p; p += SZ_B;  ushort *B2l = p; p += SZ_B;
    float*  Y3  = (float*)p;                         // 4096 x 400 fp32

    fused_front_kernel<<<TB / 4 + 392, 256, 0, stream>>>(
        fidx, emb, lin_w, quad_w, W0, W1, W2,
        A0h, A0l, B0h, B0l, B1h, B1l, B2h, B2l);

    mfma_layer_kernel<KT0, true><<<448, 64, 0, stream>>>(
        A0h, A0l, B0h, B0l, b0, g0, be0, rm0, rv0, A1h, A1l, nullptr);
    mfma_layer_kernel<KTH, true><<<448, 64, 0, stream>>>(
        A1h, A1l, B1h, B1l, b1, g1, be1, rm1, rv1, A2h, A2l, nullptr);
    mfma_layer_kernel<KTH, false><<<448, 64, 0, stream>>>(
        A2h, A2l, B2h, B2l, b2, g2, be2, rm2, rv2, nullptr, nullptr, Y3);

    out_kernel<<<TB / 4, 256, 0, stream>>>(Y3, Wout, bout, (float*)d_out);
}